// Round 6
// baseline (1441.411 us; speedup 1.0000x reference)
//
#include <hip/hip_runtime.h>

#define HID 512
#define G4 2048      // 4*HID
#define LSEQ 64
#define VOC 32000
#define EMBD 256
#define NBLK 128     // lstm blocks (one per 4 h-columns)
#define NTHR 512     // lstm threads per block (8 waves, 8-way k-split)
#define CONVBLK 128  // extra coop blocks doing fcW->bf16 conversion
#define HSZ2 (HID * 32 * 2)   // floats per per-step {h,tag} buffer (128 KB)

using s16x8 = __attribute__((ext_vector_type(8))) short;   // 8 bf16 (4 VGPR)
using f32x4 = __attribute__((ext_vector_type(4))) float;   // MFMA acc frag

__device__ inline unsigned short f2bf_rn(float x) {
    unsigned u = __float_as_uint(x);
    unsigned r = (u + 0x7fffu + ((u >> 16) & 1u)) >> 16;
    return (unsigned short)r;
}
__device__ inline float bf2f(unsigned short h) {
    return __uint_as_float(((unsigned)h) << 16);
}
__device__ inline void gload_lds16(const void* g, void* l) {
    __builtin_amdgcn_global_load_lds(
        (const __attribute__((address_space(1))) void*)g,
        (__attribute__((address_space(3))) void*)l, 16, 0, 0);
}

// ---------------------------------------------------------------------------
// Kernel 1: input projection (encoder & decoder). Produces xwT layout:
// xwT[(t*2048 + g*512 + col)*32 + b]. 64x64 tile GEMM + LDS transpose.
// ---------------------------------------------------------------------------
__global__ __launch_bounds__(256) void input_proj_kernel(
    const int* __restrict__ Xtok, const int* __restrict__ Ytok,
    const float* __restrict__ embX, const float* __restrict__ embY,
    const float* __restrict__ WE, const float* __restrict__ WD,
    const float* __restrict__ bE, const float* __restrict__ bD,
    float* __restrict__ xwE, float* __restrict__ xwD)
{
    __shared__ float Al[32][68];
    __shared__ float Bl[32][68];
    __shared__ float Cl[64][68];
    const int tid = threadIdx.x;
    const int phase = blockIdx.z;
    const int* tokens = phase ? Ytok : Xtok;
    const float* emb  = phase ? embY : embX;
    const float* W    = phase ? WD : WE;
    const float* bv   = phase ? bD : bE;
    float* outp       = phase ? xwD : xwE;

    const int m0 = blockIdx.x * 64;
    const int n0 = blockIdx.y * 64;
    const int tm = tid & 15;
    const int tn = tid >> 4;

    float acc[4][4] = {};

    for (int kc = 0; kc < EMBD; kc += 32) {
#pragma unroll
        for (int r = 0; r < 2; ++r) {
            int i = tid + r * 256;
            int am = i >> 3;
            int kq = i & 7;
            int m = m0 + am;
            int t = m >> 5, b = m & 31;
            int tok;
            if (phase) { int tt = (t == 0) ? 0 : (t - 1); tok = tokens[b * LSEQ + tt]; }
            else       { tok = tokens[b * LSEQ + t]; }
            float4 av = *(const float4*)&emb[(size_t)tok * EMBD + kc + kq * 4];
            Al[kq * 4 + 0][am] = av.x; Al[kq * 4 + 1][am] = av.y;
            Al[kq * 4 + 2][am] = av.z; Al[kq * 4 + 3][am] = av.w;
            float4 wv = *(const float4*)&W[(size_t)(n0 + am) * EMBD + kc + kq * 4];
            Bl[kq * 4 + 0][am] = wv.x; Bl[kq * 4 + 1][am] = wv.y;
            Bl[kq * 4 + 2][am] = wv.z; Bl[kq * 4 + 3][am] = wv.w;
        }
        __syncthreads();
#pragma unroll
        for (int k = 0; k < 32; ++k) {
            float4 a  = *(const float4*)&Al[k][tm * 4];
            float4 b4 = *(const float4*)&Bl[k][tn * 4];
            acc[0][0] += a.x * b4.x; acc[0][1] += a.x * b4.y; acc[0][2] += a.x * b4.z; acc[0][3] += a.x * b4.w;
            acc[1][0] += a.y * b4.x; acc[1][1] += a.y * b4.y; acc[1][2] += a.y * b4.z; acc[1][3] += a.y * b4.w;
            acc[2][0] += a.z * b4.x; acc[2][1] += a.z * b4.y; acc[2][2] += a.z * b4.z; acc[2][3] += a.z * b4.w;
            acc[3][0] += a.w * b4.x; acc[3][1] += a.w * b4.y; acc[3][2] += a.w * b4.z; acc[3][3] += a.w * b4.w;
        }
        __syncthreads();
    }

    float4 bb = *(const float4*)&bv[n0 + tn * 4];
#pragma unroll
    for (int r = 0; r < 4; ++r) {
        Cl[tn * 4 + 0][tm * 4 + r] = acc[r][0] + bb.x;
        Cl[tn * 4 + 1][tm * 4 + r] = acc[r][1] + bb.y;
        Cl[tn * 4 + 2][tm * 4 + r] = acc[r][2] + bb.z;
        Cl[tn * 4 + 3][tm * 4 + r] = acc[r][3] + bb.w;
    }
    __syncthreads();

    const int t0 = m0 >> 5;
#pragma unroll
    for (int r = 0; r < 4; ++r) {
        int f = tid + r * 256;
        int nl = f >> 4;
        int rem = f & 15;
        int tp = rem >> 3;
        int bq = rem & 7;
        float4 v = *(const float4*)&Cl[nl][tp * 32 + bq * 4];
        *(float4*)&outp[((size_t)(t0 + tp) * G4 + n0 + nl) * 32 + bq * 4] = v;
    }
}

// ---------------------------------------------------------------------------
// Kernel 2: LSTM recurrence — R4 geometry (128 blocks x 512 thr, wave-private
// htl, self-publishing {h,tag} pairs) + readiness-overlapped in-order consume:
//   - all 16 slice loads issued early (cross-step prefetched at end of s-1)
//   - per round: tag-check pending, re-issue ONLY stale slices (in flight
//     during FMA), then stage+FMA the ready PREFIX in strict slice order
//     (deterministic summation), sched_barrier pins issue-before-FMA
// Producer: ONE relaxed AGENT 8B {h, tag=s+1} store per gate thread.
// Blocks >= NBLK do the fcW->bf16 hi/lo conversion concurrently.
// ---------------------------------------------------------------------------
__global__ __launch_bounds__(512) void lstm_coop_kernel(
    const float* __restrict__ xwE, const float* __restrict__ xwD,
    const float* __restrict__ WhhE, const float* __restrict__ WhhD,
    float* __restrict__ H,
    const float* __restrict__ fcW, short* __restrict__ Bhi, short* __restrict__ Blo)
{
    __shared__ float WhhT[HID][16];      // 32 KB, [k][local row = gate*4+col]
    __shared__ float htl[HID][32];       // 64 KB, [k][b], wave-private rows
    __shared__ float part[8][16][32];    // 16 KB
    __shared__ float cst[4][32];

    const int tid = threadIdx.x;
    const int bid = blockIdx.x;

    if (bid >= NBLK) {                   // fused convW: fcW -> Bhi/Blo
        const size_t nchunk = (size_t)VOC * HID / 8;
        const size_t stride = (size_t)(gridDim.x - NBLK) * NTHR;
        for (size_t idx = (size_t)(bid - NBLK) * NTHR + tid; idx < nchunk;
             idx += stride) {
            size_t e0 = idx * 8;
            float4 v0 = *(const float4*)&fcW[e0];
            float4 v1 = *(const float4*)&fcW[e0 + 4];
            float xs[8] = {v0.x, v0.y, v0.z, v0.w, v1.x, v1.y, v1.z, v1.w};
            s16x8 h8, l8;
#pragma unroll
            for (int j = 0; j < 8; ++j) {
                unsigned short hi = f2bf_rn(xs[j]);
                h8[j] = (short)hi;
                l8[j] = (short)f2bf_rn(xs[j] - bf2f(hi));
            }
            *(s16x8*)&Bhi[e0] = h8;
            *(s16x8*)&Blo[e0] = l8;
        }
        return;
    }

    const int c0 = bid * 4;
    const int w = tid >> 6;              // wave 0..7 -> k in [64w, 64w+64)
    const int lane = tid & 63;
    const int rg = lane >> 4;            // gate 0..3
    const int bg = lane & 15;            // batch pair
    const int base = w << 4;             // first slice index for this wave
    const int jrow = (2 * lane) >> 5;    // staging row-in-slice 0..3
    const int bcol = (2 * lane) & 31;    // staging batch col

    if (tid < 128) cst[tid >> 5][tid & 31] = 0.f;

    unsigned long long va[16], vb[16];
    // prologue: issue step-0 pair loads
#pragma unroll
    for (int ii = 0; ii < 16; ++ii) {
        const unsigned long long* p = (const unsigned long long*)
            (H + (size_t)(base + ii) * 256 + lane * 4);
        va[ii] = __hip_atomic_load(p,     __ATOMIC_RELAXED, __HIP_MEMORY_SCOPE_AGENT);
        vb[ii] = __hip_atomic_load(p + 1, __ATOMIC_RELAXED, __HIP_MEMORY_SCOPE_AGENT);
    }

    for (int s = 0; s < 2 * LSEQ; ++s) {
        const int phase = s >> 6;
        const int t = s & 63;
        if (t == 0) {
            const float* Whh = phase ? WhhD : WhhE;
            for (int idx = tid; idx < 16 * 128; idx += NTHR) {
                int lr = idx >> 7;
                int kq = idx & 127;
                int grow = (lr >> 2) * HID + c0 + (lr & 3);
                float4 v = *(const float4*)&Whh[(size_t)grow * HID + kq * 4];
                WhhT[kq * 4 + 0][lr] = v.x; WhhT[kq * 4 + 1][lr] = v.y;
                WhhT[kq * 4 + 2][lr] = v.z; WhhT[kq * 4 + 3][lr] = v.w;
            }
            __syncthreads();
        }

        // xw prefetch (h-independent, overlaps the poll)
        float xg0 = 0.f, xg1 = 0.f, xg2 = 0.f, xg3 = 0.f;
        if (tid < 128) {
            int j = tid >> 5, b = tid & 31;
            const float* xw = phase ? xwD : xwE;
            size_t xb = ((size_t)t * G4 + c0 + j) * 32 + b;
            xg0 = xw[xb];
            xg1 = xw[xb + 1 * 512 * 32];
            xg2 = xw[xb + 2 * 512 * 32];
            xg3 = xw[xb + 3 * 512 * 32];
        }

        // readiness-overlapped, strictly-in-order consume
        const float* sp = H + (size_t)s * HSZ2 + lane * 4;
        float acc[4][2] = {};
        unsigned pend = 0xFFFFu, fdone = 0u;
        while (fdone != 0xFFFFu) {
            // 1) tag-check pending slices (waits on their loads)
            unsigned ready = 0u;
#pragma unroll
            for (int ii = 0; ii < 16; ++ii) {
                if (pend & (1u << ii)) {
                    int ok = ((int)(va[ii] >> 32) == s) & ((int)(vb[ii] >> 32) == s);
                    if (__all(ok)) ready |= (1u << ii);
                }
            }
            pend &= ~ready;
            pend = __builtin_amdgcn_readfirstlane(pend);
            // 2) re-issue ONLY still-stale slices (in flight during FMA below)
#pragma unroll
            for (int ii = 0; ii < 16; ++ii) {
                if (pend & (1u << ii)) {
                    const unsigned long long* p =
                        (const unsigned long long*)(sp + (size_t)(base + ii) * 256);
                    va[ii] = __hip_atomic_load(p,     __ATOMIC_RELAXED, __HIP_MEMORY_SCOPE_AGENT);
                    vb[ii] = __hip_atomic_load(p + 1, __ATOMIC_RELAXED, __HIP_MEMORY_SCOPE_AGENT);
                }
            }
            __builtin_amdgcn_sched_barrier(0);
            // 3) stage + FMA the ready prefix, strict slice order (deterministic)
            const unsigned lowpend = pend ? (unsigned)__builtin_ctz(pend) : 16u;
            unsigned todo = 0u;
#pragma unroll
            for (int ii = 0; ii < 16; ++ii)
                if (!((fdone >> ii) & 1u) && (unsigned)ii < lowpend) todo |= (1u << ii);
#pragma unroll
            for (int ii = 0; ii < 16; ++ii) {
                if (todo & (1u << ii)) {
                    float2 hv2;
                    hv2.x = __uint_as_float((unsigned)va[ii]);
                    hv2.y = __uint_as_float((unsigned)vb[ii]);
                    *(float2*)&htl[4 * (base + ii) + jrow][bcol] = hv2;
                }
            }
#pragma unroll
            for (int ii = 0; ii < 16; ++ii) {
                if (todo & (1u << ii)) {
                    int kbase = 4 * (base + ii);
#pragma unroll
                    for (int kd = 0; kd < 4; ++kd) {
                        int k = kbase + kd;
                        float4 wv = *(const float4*)&WhhT[k][rg * 4];
                        float2 hv = *(const float2*)&htl[k][bg * 2];
                        acc[0][0] += wv.x * hv.x; acc[0][1] += wv.x * hv.y;
                        acc[1][0] += wv.y * hv.x; acc[1][1] += wv.y * hv.y;
                        acc[2][0] += wv.z * hv.x; acc[2][1] += wv.z * hv.y;
                        acc[3][0] += wv.w * hv.x; acc[3][1] += wv.w * hv.y;
                    }
                    fdone |= (1u << ii);
                }
            }
            if (!todo && !ready) __builtin_amdgcn_s_sleep(1);
        }

        // cross-step prefetch: issue step-(s+1) pair loads before the reduce
        if (s + 1 < 2 * LSEQ) {
            const float* spn = H + (size_t)(s + 1) * HSZ2 + lane * 4;
#pragma unroll
            for (int ii = 0; ii < 16; ++ii) {
                const unsigned long long* p =
                    (const unsigned long long*)(spn + (size_t)(base + ii) * 256);
                va[ii] = __hip_atomic_load(p,     __ATOMIC_RELAXED, __HIP_MEMORY_SCOPE_AGENT);
                vb[ii] = __hip_atomic_load(p + 1, __ATOMIC_RELAXED, __HIP_MEMORY_SCOPE_AGENT);
            }
        }

#pragma unroll
        for (int ri = 0; ri < 4; ++ri) {
            float2 pv = make_float2(acc[ri][0], acc[ri][1]);
            *(float2*)&part[w][rg * 4 + ri][bg * 2] = pv;
        }
        __syncthreads();

        if (tid < 128) {                  // gates + state update + publish
            int j = tid >> 5, b = tid & 31;
            float gi = xg0, gf = xg1, gg = xg2, go = xg3;
#pragma unroll
            for (int q = 0; q < 8; ++q) {
                gi += part[q][j][b];      gf += part[q][4 + j][b];
                gg += part[q][8 + j][b];  go += part[q][12 + j][b];
            }
            float si = 1.f / (1.f + __expf(-gi));
            float sf = 1.f / (1.f + __expf(-gf));
            float so = 1.f / (1.f + __expf(-go));
            float tg = tanhf(gg);
            float c = sf * cst[j][b] + si * tg;
            cst[j][b] = c;
            float h = so * tanhf(c);
            unsigned long long pv =
                ((unsigned long long)(unsigned)(s + 1) << 32) | __float_as_uint(h);
            __hip_atomic_store(
                (unsigned long long*)&H[(size_t)(s + 1) * HSZ2 + (size_t)(c0 * 32 + j * 32 + b) * 2],
                pv, __ATOMIC_RELAXED, __HIP_MEMORY_SCOPE_AGENT);
        }
        asm volatile("" ::: "memory");
        __builtin_amdgcn_s_barrier();     // part WAR only; no vmcnt drain
    }
}

// ---------------------------------------------------------------------------
// Kernel 4a (fallback path only): fcW (f32) -> Bhi/Blo (bf16).
// ---------------------------------------------------------------------------
__global__ __launch_bounds__(256) void convW_kernel(
    const float* __restrict__ W, short* __restrict__ Bhi, short* __restrict__ Blo)
{
    size_t idx = (size_t)blockIdx.x * 256 + threadIdx.x;
    size_t e0 = idx * 8;
    float4 v0 = *(const float4*)&W[e0];
    float4 v1 = *(const float4*)&W[e0 + 4];
    float xs[8] = {v0.x, v0.y, v0.z, v0.w, v1.x, v1.y, v1.z, v1.w};
    s16x8 h8, l8;
#pragma unroll
    for (int j = 0; j < 8; ++j) {
        unsigned short hi = f2bf_rn(xs[j]);
        h8[j] = (short)hi;
        l8[j] = (short)f2bf_rn(xs[j] - bf2f(hi));
    }
    *(s16x8*)&Bhi[e0] = h8;
    *(s16x8*)&Blo[e0] = l8;
}

// ---------------------------------------------------------------------------
// Kernel 4b: decoder H ({h,tag} pairs) -> Ahi/Alo bf16 [2048][512].
// ---------------------------------------------------------------------------
__global__ __launch_bounds__(256) void convA_kernel(
    const float* __restrict__ H65, short* __restrict__ Ahi, short* __restrict__ Alo)
{
    int idx = blockIdx.x * 256 + threadIdx.x;   // 131072 = 2048 m x 64 k8
    int m = idx & 2047;
    int k8 = idx >> 11;
    int t = m >> 5, b = m & 31;
    const float* Hs = H65 + (size_t)t * HSZ2;
    s16x8 h8, l8;
#pragma unroll
    for (int j = 0; j < 8; ++j) {
        int k = k8 * 8 + j;
        float x = Hs[(size_t)(k * 32 + b) * 2];
        unsigned short hi = f2bf_rn(x);
        h8[j] = (short)hi;
        l8[j] = (short)f2bf_rn(x - bf2f(hi));
    }
    *(s16x8*)&Ahi[(size_t)m * 512 + k8 * 8] = h8;
    *(s16x8*)&Alo[(size_t)m * 512 + k8 * 8] = l8;
}

// ---------------------------------------------------------------------------
// Kernel 5: FC via split-bf16 MFMA. C = Ahi*Bhi + Alo*Bhi + Ahi*Blo (+bias).
// 128x128 tile, 4 waves, K-step 64, global_load_lds(16), 16x16x32 bf16 MFMA.
// ---------------------------------------------------------------------------
__global__ __launch_bounds__(256) void fc_mfma_kernel(
    const short* __restrict__ Ahi, const short* __restrict__ Alo,
    const short* __restrict__ Bhi, const short* __restrict__ Blo,
    const float* __restrict__ bias, float* __restrict__ out)
{
    __shared__ short As[128 * 64];
    __shared__ short Bs[128 * 64];

    const int bi = blockIdx.x;
    const int wg = (bi & 7) * 500 + (bi >> 3);    // XCD-contiguous remap
    const int mt = wg & 15, nt = wg >> 4;
    const int m0 = mt * 128, n0 = nt * 128;
    const int tid = threadIdx.x;
    const int w = tid >> 6, lane = tid & 63;
    const int wm = w >> 1, wn = w & 1;
    const int srow = (lane >> 3);
    const int scol = (lane & 7) * 8;

    f32x4 acc[4][4] = {};

    for (int ks = 0; ks < 24; ++ks) {
        const int seg = ks >> 3;                  // 0: hi*hi 1: lo*hi 2: hi*lo
        const int kco = (ks & 7) * 64;
        const short* Asrc = (seg == 1) ? Alo : Ahi;
        const short* Bsrc = (seg == 2) ? Blo : Bhi;
#pragma unroll
        for (int i = 0; i < 4; ++i) {
            int row = w * 32 + i * 8 + srow;
            gload_lds16(&Asrc[(size_t)(m0 + row) * 512 + kco + scol],
                        (void*)&As[w * 2048 + i * 512]);
            gload_lds16(&Bsrc[(size_t)(n0 + row) * 512 + kco + scol],
                        (void*)&Bs[w * 2048 + i * 512]);
        }
        __syncthreads();

#pragma unroll
        for (int kk = 0; kk < 2; ++kk) {
            s16x8 af[4], bf[4];
#pragma unroll
            for (int f = 0; f < 4; ++f) {
                af[f] = *(const s16x8*)&As[(wm * 64 + f * 16 + (lane & 15)) * 64 + kk * 32 + (lane >> 4) * 8];
                bf[f] = *(const s16x8*)&Bs[(wn * 64 + f * 16 + (lane & 15)) * 64 + kk * 32 + (lane >> 4) * 8];
            }
#pragma unroll
            for (int fm = 0; fm < 4; ++fm)
#pragma unroll
                for (int fn = 0; fn < 4; ++fn)
                    acc[fm][fn] = __builtin_amdgcn_mfma_f32_16x16x32_bf16(
                        af[fm], bf[fn], acc[fm][fn], 0, 0, 0);
        }
        __syncthreads();
    }

    float bb[4];
#pragma unroll
    for (int fn = 0; fn < 4; ++fn)
        bb[fn] = bias[n0 + wn * 64 + fn * 16 + (lane & 15)];

#pragma unroll
    for (int fm = 0; fm < 4; ++fm) {
        int mbase = m0 + wm * 64 + fm * 16 + (lane >> 4) * 4;
#pragma unroll
        for (int r = 0; r < 4; ++r) {
            int m = mbase + r;
            int t = m >> 5, b = m & 31;
            float* orow = out + (size_t)(b * LSEQ + t) * VOC;
#pragma unroll
            for (int fn = 0; fn < 4; ++fn)
                orow[n0 + wn * 64 + fn * 16 + (lane & 15)] = acc[fm][fn][r] + bb[fn];
        }
    }
}

// ---------------------------------------------------------------------------
extern "C" void kernel_launch(void* const* d_in, const int* in_sizes, int n_in,
                              void* d_out, int out_size, void* d_ws, size_t ws_size,
                              hipStream_t stream)
{
    const int*   X    = (const int*)d_in[0];
    const int*   y    = (const int*)d_in[1];
    // d_in[2] = teacher_forcing (always 1, unused)
    const float* embX = (const float*)d_in[3];
    const float* WihE = (const float*)d_in[4];
    const float* WhhE = (const float*)d_in[5];
    const float* bE   = (const float*)d_in[6];
    const float* embY = (const float*)d_in[7];
    const float* WihD = (const float*)d_in[8];
    const float* WhhD = (const float*)d_in[9];
    const float* bD   = (const float*)d_in[10];
    const float* fcW  = (const float*)d_in[11];
    const float* fcB  = (const float*)d_in[12];
    float* out = (float*)d_out;

    char* ws = (char*)d_ws;
    const size_t XW_BYTES = (size_t)2048 * 2048 * 4;          // 16 MB each
    const size_t H_BYTES  = (size_t)129 * HSZ2 * 4;           // 16.9 MB
    const size_t A_BYTES  = (size_t)2048 * HID * 2;           // 2 MB each
    const size_t B_BYTES  = (size_t)VOC * HID * 2;            // 32 MB each

    const bool fuse = ws_size >= 2 * B_BYTES + 2 * XW_BYTES + H_BYTES + 2 * A_BYTES;
    float *xwE, *xwD, *H; short *Ahi, *Alo, *Bhi, *Blo;
    if (fuse) {
        // non-aliased layout: Bhi/Blo written concurrently with lstm
        Bhi = (short*)(ws);
        Blo = (short*)(ws + B_BYTES);
        xwE = (float*)(ws + 2 * B_BYTES);
        xwD = (float*)(ws + 2 * B_BYTES + XW_BYTES);
        H   = (float*)(ws + 2 * B_BYTES + 2 * XW_BYTES);
        Ahi = (short*)(ws + 2 * B_BYTES + 2 * XW_BYTES + H_BYTES);
        Alo = (short*)(ws + 2 * B_BYTES + 2 * XW_BYTES + H_BYTES + A_BYTES);
    } else {
        // fallback layout: Bhi aliases dead xw region, convW runs after lstm
        xwE = (float*)(ws);
        xwD = (float*)(ws + XW_BYTES);
        H   = (float*)(ws + 2 * XW_BYTES);
        Ahi = (short*)(ws + 2 * XW_BYTES + H_BYTES);
        Alo = (short*)(ws + 2 * XW_BYTES + H_BYTES + A_BYTES);
        Bhi = (short*)(ws);
        Blo = (short*)(ws + 2 * XW_BYTES + H_BYTES + 2 * A_BYTES);
    }

    // reset all H tags every launch (honest sync across graph replays);
    // H[0] = {h=0, tag=0} is the step-0 input.
    hipMemsetAsync((void*)H, 0, H_BYTES, stream);

    input_proj_kernel<<<dim3(32, 32, 2), 256, 0, stream>>>(
        X, y, embX, embY, WihE, WihD, bE, bD, xwE, xwD);

    {
        const float* a0 = xwE; const float* a1 = xwD;
        const float* a2 = WhhE; const float* a3 = WhhD;
        float* a4 = H;
        const float* a5 = fcW; short* a6 = Bhi; short* a7 = Blo;
        void* args[] = {&a0, &a1, &a2, &a3, &a4, &a5, &a6, &a7};
        hipLaunchCooperativeKernel((const void*)lstm_coop_kernel,
                                   dim3(fuse ? (NBLK + CONVBLK) : NBLK), dim3(NTHR),
                                   args, 0, stream);
    }

    if (!fuse)
        convW_kernel<<<8000, 256, 0, stream>>>(fcW, Bhi, Blo);

    convA_kernel<<<512, 256, 0, stream>>>(H + (size_t)65 * HSZ2, Ahi, Alo);

    fc_mfma_kernel<<<4000, 256, 0, stream>>>(Ahi, Alo, Bhi, Blo, fcB, out);
}

// Round 7
// 1165.496 us; speedup vs baseline: 1.2367x; 1.2367x over previous
//
#include <hip/hip_runtime.h>

#define HID 512
#define G4 2048      // 4*HID
#define LSEQ 64
#define VOC 32000
#define EMBD 256
#define NBLK 128     // lstm blocks (one per 4 h-columns)
#define NTHR 512     // lstm threads per block (8 waves, 8-way k-split)
#define HSZ2 (HID * 32 * 2)   // floats per per-step {h,tag} buffer (128 KB)

using s16x8 = __attribute__((ext_vector_type(8))) short;   // 8 bf16 (4 VGPR)
using f32x4 = __attribute__((ext_vector_type(4))) float;   // MFMA acc frag
using uintx4 = __attribute__((ext_vector_type(4))) unsigned; // 16B load payload

__device__ inline unsigned short f2bf_rn(float x) {
    unsigned u = __float_as_uint(x);
    unsigned r = (u + 0x7fffu + ((u >> 16) & 1u)) >> 16;
    return (unsigned short)r;
}
__device__ inline float bf2f(unsigned short h) {
    return __uint_as_float(((unsigned)h) << 16);
}
__device__ inline void gload_lds16(const void* g, void* l) {
    __builtin_amdgcn_global_load_lds(
        (const __attribute__((address_space(1))) void*)g,
        (__attribute__((address_space(3))) void*)l, 16, 0, 0);
}

// ---------------------------------------------------------------------------
// Kernel 1: input projection (encoder & decoder). Produces xwT layout:
// xwT[(t*2048 + g*512 + col)*32 + b]. 64x64 tile GEMM + LDS transpose.
// ---------------------------------------------------------------------------
__global__ __launch_bounds__(256) void input_proj_kernel(
    const int* __restrict__ Xtok, const int* __restrict__ Ytok,
    const float* __restrict__ embX, const float* __restrict__ embY,
    const float* __restrict__ WE, const float* __restrict__ WD,
    const float* __restrict__ bE, const float* __restrict__ bD,
    float* __restrict__ xwE, float* __restrict__ xwD)
{
    __shared__ float Al[32][68];
    __shared__ float Bl[32][68];
    __shared__ float Cl[64][68];
    const int tid = threadIdx.x;
    const int phase = blockIdx.z;
    const int* tokens = phase ? Ytok : Xtok;
    const float* emb  = phase ? embY : embX;
    const float* W    = phase ? WD : WE;
    const float* bv   = phase ? bD : bE;
    float* outp       = phase ? xwD : xwE;

    const int m0 = blockIdx.x * 64;
    const int n0 = blockIdx.y * 64;
    const int tm = tid & 15;
    const int tn = tid >> 4;

    float acc[4][4] = {};

    for (int kc = 0; kc < EMBD; kc += 32) {
#pragma unroll
        for (int r = 0; r < 2; ++r) {
            int i = tid + r * 256;
            int am = i >> 3;
            int kq = i & 7;
            int m = m0 + am;
            int t = m >> 5, b = m & 31;
            int tok;
            if (phase) { int tt = (t == 0) ? 0 : (t - 1); tok = tokens[b * LSEQ + tt]; }
            else       { tok = tokens[b * LSEQ + t]; }
            float4 av = *(const float4*)&emb[(size_t)tok * EMBD + kc + kq * 4];
            Al[kq * 4 + 0][am] = av.x; Al[kq * 4 + 1][am] = av.y;
            Al[kq * 4 + 2][am] = av.z; Al[kq * 4 + 3][am] = av.w;
            float4 wv = *(const float4*)&W[(size_t)(n0 + am) * EMBD + kc + kq * 4];
            Bl[kq * 4 + 0][am] = wv.x; Bl[kq * 4 + 1][am] = wv.y;
            Bl[kq * 4 + 2][am] = wv.z; Bl[kq * 4 + 3][am] = wv.w;
        }
        __syncthreads();
#pragma unroll
        for (int k = 0; k < 32; ++k) {
            float4 a  = *(const float4*)&Al[k][tm * 4];
            float4 b4 = *(const float4*)&Bl[k][tn * 4];
            acc[0][0] += a.x * b4.x; acc[0][1] += a.x * b4.y; acc[0][2] += a.x * b4.z; acc[0][3] += a.x * b4.w;
            acc[1][0] += a.y * b4.x; acc[1][1] += a.y * b4.y; acc[1][2] += a.y * b4.z; acc[1][3] += a.y * b4.w;
            acc[2][0] += a.z * b4.x; acc[2][1] += a.z * b4.y; acc[2][2] += a.z * b4.z; acc[2][3] += a.z * b4.w;
            acc[3][0] += a.w * b4.x; acc[3][1] += a.w * b4.y; acc[3][2] += a.w * b4.z; acc[3][3] += a.w * b4.w;
        }
        __syncthreads();
    }

    float4 bb = *(const float4*)&bv[n0 + tn * 4];
#pragma unroll
    for (int r = 0; r < 4; ++r) {
        Cl[tn * 4 + 0][tm * 4 + r] = acc[r][0] + bb.x;
        Cl[tn * 4 + 1][tm * 4 + r] = acc[r][1] + bb.y;
        Cl[tn * 4 + 2][tm * 4 + r] = acc[r][2] + bb.z;
        Cl[tn * 4 + 3][tm * 4 + r] = acc[r][3] + bb.w;
    }
    __syncthreads();

    const int t0 = m0 >> 5;
#pragma unroll
    for (int r = 0; r < 4; ++r) {
        int f = tid + r * 256;
        int nl = f >> 4;
        int rem = f & 15;
        int tp = rem >> 3;
        int bq = rem & 7;
        float4 v = *(const float4*)&Cl[nl][tp * 32 + bq * 4];
        *(float4*)&outp[((size_t)(t0 + tp) * G4 + n0 + nl) * 32 + bq * 4] = v;
    }
}

// ---------------------------------------------------------------------------
// Kernel 2: LSTM recurrence — R4 geometry (128 blk x 512 thr, 8-way k-split,
// wave-private htl, self-publishing {h,tag} pairs) with request-count surgery:
//   - slice loads are 16B global_load_dwordx4 sc1 (agent scope, one request
//     per 2 pairs); each aligned 8B half is atomic, pairs self-validate
//   - retry rounds re-issue ONLY still-stale slices (ready data held in regs)
//   - FMA runs once after all 16 ready, fixed slice order => deterministic
//   - part[2] double-buffer; ONE raw lgkmcnt+s_barrier per step (no end
//     barrier): waves 2-7 start step s+1 poll while waves 0-1 do gates+publish
// ---------------------------------------------------------------------------
__global__ __launch_bounds__(512) void lstm_coop_kernel(
    const float* __restrict__ xwE, const float* __restrict__ xwD,
    const float* __restrict__ WhhE, const float* __restrict__ WhhD,
    float* __restrict__ H)
{
    __shared__ float WhhT[HID][16];      // 32 KB, [k][local row = gate*4+col]
    __shared__ float htl[HID][32];       // 64 KB, [k][b], wave-private rows
    __shared__ float part[2][8][16][32]; // 32 KB, ping-pong by step parity

    const int tid = threadIdx.x;
    const int bid = blockIdx.x;
    const int c0 = bid * 4;
    const int w = tid >> 6;              // wave 0..7 -> k in [64w, 64w+64)
    const int lane = tid & 63;
    const int rg = lane >> 4;            // gate 0..3
    const int bg = lane & 15;            // batch pair
    const int base = w << 4;             // first slice index for this wave
    const int jrow = (2 * lane) >> 5;    // staging row-in-slice 0..3
    const int bcol = (2 * lane) & 31;    // staging batch col
    float creg = 0.f;                    // cell state (gate threads, tid<128)

    for (int s = 0; s < 2 * LSEQ; ++s) {
        const int phase = s >> 6;
        const int t = s & 63;
        if (t == 0) {
            // all waves' FMA of the previous step completed before the part
            // barrier => safe to overwrite WhhT here (gates read part, not WhhT)
            const float* Whh = phase ? WhhD : WhhE;
            for (int idx = tid; idx < 16 * 128; idx += NTHR) {
                int lr = idx >> 7;
                int kq = idx & 127;
                int grow = (lr >> 2) * HID + c0 + (lr & 3);
                float4 v = *(const float4*)&Whh[(size_t)grow * HID + kq * 4];
                WhhT[kq * 4 + 0][lr] = v.x; WhhT[kq * 4 + 1][lr] = v.y;
                WhhT[kq * 4 + 2][lr] = v.z; WhhT[kq * 4 + 3][lr] = v.w;
            }
            __syncthreads();
        }

        // xw prefetch (h-independent, overlaps the poll)
        float xg0 = 0.f, xg1 = 0.f, xg2 = 0.f, xg3 = 0.f;
        if (tid < 128) {
            int j = tid >> 5, b = tid & 31;
            const float* xw = phase ? xwD : xwE;
            size_t xb = ((size_t)t * G4 + c0 + j) * 32 + b;
            xg0 = xw[xb];
            xg1 = xw[xb + 1 * 512 * 32];
            xg2 = xw[xb + 2 * 512 * 32];
            xg3 = xw[xb + 3 * 512 * 32];
        }

        // poll: 16B sc1 loads, selective reload of stale slices only
        const float* sp0 = H + (size_t)s * HSZ2 + (size_t)base * 256 + (size_t)lane * 4;
        uintx4 v[16];
        unsigned pend = 0xffffu;
        do {
#pragma unroll
            for (int ii = 0; ii < 16; ++ii) {
                if (pend & (1u << ii)) {
                    asm volatile("global_load_dwordx4 %0, %1, off offset:%c2 sc1"
                                 : "=v"(v[ii])
                                 : "v"(sp0 + (ii & ~3) * 256), "i"((ii & 3) * 1024));
                }
            }
            asm volatile("s_waitcnt vmcnt(0)" ::: "memory");
            __builtin_amdgcn_sched_barrier(0);
            int ok[16];
            int okall = 1;
#pragma unroll
            for (int ii = 0; ii < 16; ++ii) {
                ok[ii] = 1;
                if (pend & (1u << ii)) {
                    ok[ii] = (v[ii].y == (unsigned)s) & (v[ii].w == (unsigned)s);
                    okall &= ok[ii];
                }
            }
            if (__all(okall)) break;     // fast path: everything ready
            unsigned still = 0u;
#pragma unroll
            for (int ii = 0; ii < 16; ++ii)
                if ((pend & (1u << ii)) && !__all(ok[ii])) still |= (1u << ii);
            pend = still;                // uniform (built from __all results)
            if (pend) __builtin_amdgcn_s_sleep(1);
        } while (pend);

        // stage to wave-private LDS region (rows 64w..64w+63)
#pragma unroll
        for (int ii = 0; ii < 16; ++ii) {
            float2 hv2 = make_float2(__uint_as_float(v[ii].x),
                                     __uint_as_float(v[ii].z));
            *(float2*)&htl[4 * (base + ii) + jrow][bcol] = hv2;
        }

        // FMA over this wave's k-range
        float acc[4][2] = {};
        const int k0 = w << 6;
#pragma unroll 8
        for (int k = k0; k < k0 + 64; ++k) {
            float4 wv = *(const float4*)&WhhT[k][rg * 4];
            float2 hv = *(const float2*)&htl[k][bg * 2];
            acc[0][0] += wv.x * hv.x; acc[0][1] += wv.x * hv.y;
            acc[1][0] += wv.y * hv.x; acc[1][1] += wv.y * hv.y;
            acc[2][0] += wv.z * hv.x; acc[2][1] += wv.z * hv.y;
            acc[3][0] += wv.w * hv.x; acc[3][1] += wv.w * hv.y;
        }

        const int pidx = s & 1;
#pragma unroll
        for (int ri = 0; ri < 4; ++ri) {
            float2 pv = make_float2(acc[ri][0], acc[ri][1]);
            *(float2*)&part[pidx][w][rg * 4 + ri][bg * 2] = pv;
        }
        asm volatile("s_waitcnt lgkmcnt(0)\ns_barrier" ::: "memory"); // the ONE barrier

        // gates + state update + publish (waves 0-1); waves 2-7 are already
        // polling step s+1 (part is double-buffered, htl/WhhT wave-private)
        if (tid < 128) {
            int j = tid >> 5, b = tid & 31;
            float gi = xg0, gf = xg1, gg = xg2, go = xg3;
#pragma unroll
            for (int q = 0; q < 8; ++q) {
                gi += part[pidx][q][j][b];      gf += part[pidx][q][4 + j][b];
                gg += part[pidx][q][8 + j][b];  go += part[pidx][q][12 + j][b];
            }
            float si = 1.f / (1.f + __expf(-gi));
            float sf = 1.f / (1.f + __expf(-gf));
            float so = 1.f / (1.f + __expf(-go));
            float tg = tanhf(gg);
            float c = sf * creg + si * tg;
            creg = c;
            float h = so * tanhf(c);
            unsigned long long pv =
                ((unsigned long long)(unsigned)(s + 1) << 32) | __float_as_uint(h);
            __hip_atomic_store(
                (unsigned long long*)&H[(size_t)(s + 1) * HSZ2 + (size_t)(c0 * 32 + j * 32 + b) * 2],
                pv, __ATOMIC_RELAXED, __HIP_MEMORY_SCOPE_AGENT);
        }
        // no end-of-step barrier
    }
}

// ---------------------------------------------------------------------------
// Kernel 4a: fcW (f32) -> Bhi/Blo (bf16). Runs after lstm (xw region dead).
// ---------------------------------------------------------------------------
__global__ __launch_bounds__(256) void convW_kernel(
    const float* __restrict__ W, short* __restrict__ Bhi, short* __restrict__ Blo)
{
    size_t idx = (size_t)blockIdx.x * 256 + threadIdx.x;
    size_t e0 = idx * 8;
    float4 v0 = *(const float4*)&W[e0];
    float4 v1 = *(const float4*)&W[e0 + 4];
    float xs[8] = {v0.x, v0.y, v0.z, v0.w, v1.x, v1.y, v1.z, v1.w};
    s16x8 h8, l8;
#pragma unroll
    for (int j = 0; j < 8; ++j) {
        unsigned short hi = f2bf_rn(xs[j]);
        h8[j] = (short)hi;
        l8[j] = (short)f2bf_rn(xs[j] - bf2f(hi));
    }
    *(s16x8*)&Bhi[e0] = h8;
    *(s16x8*)&Blo[e0] = l8;
}

// ---------------------------------------------------------------------------
// Kernel 4b: decoder H ({h,tag} pairs) -> Ahi/Alo bf16 [2048][512].
// ---------------------------------------------------------------------------
__global__ __launch_bounds__(256) void convA_kernel(
    const float* __restrict__ H65, short* __restrict__ Ahi, short* __restrict__ Alo)
{
    int idx = blockIdx.x * 256 + threadIdx.x;   // 131072 = 2048 m x 64 k8
    int m = idx & 2047;
    int k8 = idx >> 11;
    int t = m >> 5, b = m & 31;
    const float* Hs = H65 + (size_t)t * HSZ2;
    s16x8 h8, l8;
#pragma unroll
    for (int j = 0; j < 8; ++j) {
        int k = k8 * 8 + j;
        float x = Hs[(size_t)(k * 32 + b) * 2];
        unsigned short hi = f2bf_rn(x);
        h8[j] = (short)hi;
        l8[j] = (short)f2bf_rn(x - bf2f(hi));
    }
    *(s16x8*)&Ahi[(size_t)m * 512 + k8 * 8] = h8;
    *(s16x8*)&Alo[(size_t)m * 512 + k8 * 8] = l8;
}

// ---------------------------------------------------------------------------
// Kernel 5: FC via split-bf16 MFMA. C = Ahi*Bhi + Alo*Bhi + Ahi*Blo (+bias).
// 128x128 tile, 4 waves, K-step 64, global_load_lds(16), 16x16x32 bf16 MFMA.
// ---------------------------------------------------------------------------
__global__ __launch_bounds__(256) void fc_mfma_kernel(
    const short* __restrict__ Ahi, const short* __restrict__ Alo,
    const short* __restrict__ Bhi, const short* __restrict__ Blo,
    const float* __restrict__ bias, float* __restrict__ out)
{
    __shared__ short As[128 * 64];
    __shared__ short Bs[128 * 64];

    const int bi = blockIdx.x;
    const int wg = (bi & 7) * 500 + (bi >> 3);    // XCD-contiguous remap
    const int mt = wg & 15, nt = wg >> 4;
    const int m0 = mt * 128, n0 = nt * 128;
    const int tid = threadIdx.x;
    const int w = tid >> 6, lane = tid & 63;
    const int wm = w >> 1, wn = w & 1;
    const int srow = (lane >> 3);
    const int scol = (lane & 7) * 8;

    f32x4 acc[4][4] = {};

    for (int ks = 0; ks < 24; ++ks) {
        const int seg = ks >> 3;                  // 0: hi*hi 1: lo*hi 2: hi*lo
        const int kco = (ks & 7) * 64;
        const short* Asrc = (seg == 1) ? Alo : Ahi;
        const short* Bsrc = (seg == 2) ? Blo : Bhi;
#pragma unroll
        for (int i = 0; i < 4; ++i) {
            int row = w * 32 + i * 8 + srow;
            gload_lds16(&Asrc[(size_t)(m0 + row) * 512 + kco + scol],
                        (void*)&As[w * 2048 + i * 512]);
            gload_lds16(&Bsrc[(size_t)(n0 + row) * 512 + kco + scol],
                        (void*)&Bs[w * 2048 + i * 512]);
        }
        __syncthreads();

#pragma unroll
        for (int kk = 0; kk < 2; ++kk) {
            s16x8 af[4], bf[4];
#pragma unroll
            for (int f = 0; f < 4; ++f) {
                af[f] = *(const s16x8*)&As[(wm * 64 + f * 16 + (lane & 15)) * 64 + kk * 32 + (lane >> 4) * 8];
                bf[f] = *(const s16x8*)&Bs[(wn * 64 + f * 16 + (lane & 15)) * 64 + kk * 32 + (lane >> 4) * 8];
            }
#pragma unroll
            for (int fm = 0; fm < 4; ++fm)
#pragma unroll
                for (int fn = 0; fn < 4; ++fn)
                    acc[fm][fn] = __builtin_amdgcn_mfma_f32_16x16x32_bf16(
                        af[fm], bf[fn], acc[fm][fn], 0, 0, 0);
        }
        __syncthreads();
    }

    float bb[4];
#pragma unroll
    for (int fn = 0; fn < 4; ++fn)
        bb[fn] = bias[n0 + wn * 64 + fn * 16 + (lane & 15)];

#pragma unroll
    for (int fm = 0; fm < 4; ++fm) {
        int mbase = m0 + wm * 64 + fm * 16 + (lane >> 4) * 4;
#pragma unroll
        for (int r = 0; r < 4; ++r) {
            int m = mbase + r;
            int t = m >> 5, b = m & 31;
            float* orow = out + (size_t)(b * LSEQ + t) * VOC;
#pragma unroll
            for (int fn = 0; fn < 4; ++fn)
                orow[n0 + wn * 64 + fn * 16 + (lane & 15)] = acc[fm][fn][r] + bb[fn];
        }
    }
}

// ---------------------------------------------------------------------------
extern "C" void kernel_launch(void* const* d_in, const int* in_sizes, int n_in,
                              void* d_out, int out_size, void* d_ws, size_t ws_size,
                              hipStream_t stream)
{
    const int*   X    = (const int*)d_in[0];
    const int*   y    = (const int*)d_in[1];
    // d_in[2] = teacher_forcing (always 1, unused)
    const float* embX = (const float*)d_in[3];
    const float* WihE = (const float*)d_in[4];
    const float* WhhE = (const float*)d_in[5];
    const float* bE   = (const float*)d_in[6];
    const float* embY = (const float*)d_in[7];
    const float* WihD = (const float*)d_in[8];
    const float* WhhD = (const float*)d_in[9];
    const float* bD   = (const float*)d_in[10];
    const float* fcW  = (const float*)d_in[11];
    const float* fcB  = (const float*)d_in[12];
    float* out = (float*)d_out;

    char* ws = (char*)d_ws;
    const size_t XW_BYTES = (size_t)2048 * 2048 * 4;          // 16 MB each
    const size_t H_BYTES  = (size_t)129 * HSZ2 * 4;           // 16.9 MB
    const size_t A_BYTES  = (size_t)2048 * HID * 2;           // 2 MB each

    // R4-proven layout: Bhi aliases the dead xw region after the lstm.
    float* xwE = (float*)(ws);
    float* xwD = (float*)(ws + XW_BYTES);
    float* H   = (float*)(ws + 2 * XW_BYTES);
    short* Ahi = (short*)(ws + 2 * XW_BYTES + H_BYTES);
    short* Alo = (short*)(ws + 2 * XW_BYTES + H_BYTES + A_BYTES);
    short* Bhi = (short*)(ws);                                 // aliases xw (dead)
    short* Blo = (short*)(ws + 2 * XW_BYTES + H_BYTES + 2 * A_BYTES);

    // reset all H tags every launch (honest sync across graph replays);
    // H[0] = {h=0, tag=0} is the step-0 input.
    hipMemsetAsync((void*)H, 0, H_BYTES, stream);

    input_proj_kernel<<<dim3(32, 32, 2), 256, 0, stream>>>(
        X, y, embX, embY, WihE, WihD, bE, bD, xwE, xwD);

    {
        const float* a0 = xwE; const float* a1 = xwD;
        const float* a2 = WhhE; const float* a3 = WhhD;
        float* a4 = H;
        void* args[] = {&a0, &a1, &a2, &a3, &a4};
        hipLaunchCooperativeKernel((const void*)lstm_coop_kernel, dim3(NBLK), dim3(NTHR),
                                   args, 0, stream);
    }

    convW_kernel<<<8000, 256, 0, stream>>>(fcW, Bhi, Blo);   // xw region now dead
    convA_kernel<<<512, 256, 0, stream>>>(H + (size_t)65 * HSZ2, Ahi, Alo);

    fc_mfma_kernel<<<4000, 256, 0, stream>>>(Ahi, Alo, Bhi, Blo, fcB, out);
}

// Round 8
// 1079.308 us; speedup vs baseline: 1.3355x; 1.0799x over previous
//
#include <hip/hip_runtime.h>

#define HID 512
#define G4 2048      // 4*HID
#define LSEQ 64
#define VOC 32000
#define EMBD 256
#define NBLK 32      // lstm blocks (one per 16 h-columns, 64 gate rows)
#define NTHR 512     // 8 waves = 4 row-tiles x 2 batch-tiles
#define HSZ2 (HID * 32 * 2)   // u32 units per per-step {hilo,tag} buffer (128 KB)

using s16x8 = __attribute__((ext_vector_type(8))) short;   // 8 bf16 (4 VGPR)
using f32x4 = __attribute__((ext_vector_type(4))) float;   // MFMA acc frag
using uintx4 = __attribute__((ext_vector_type(4))) unsigned; // 16B load payload

__device__ inline unsigned short f2bf_rn(float x) {
    unsigned u = __float_as_uint(x);
    unsigned r = (u + 0x7fffu + ((u >> 16) & 1u)) >> 16;
    return (unsigned short)r;
}
__device__ inline float bf2f(unsigned short h) {
    return __uint_as_float(((unsigned)h) << 16);
}
__device__ inline void gload_lds16(const void* g, void* l) {
    __builtin_amdgcn_global_load_lds(
        (const __attribute__((address_space(1))) void*)g,
        (__attribute__((address_space(3))) void*)l, 16, 0, 0);
}

// ---------------------------------------------------------------------------
// Kernel 1: input projection (encoder & decoder). Produces xwT layout:
// xwT[(t*2048 + g*512 + col)*32 + b]. 64x64 tile GEMM + LDS transpose.
// ---------------------------------------------------------------------------
__global__ __launch_bounds__(256) void input_proj_kernel(
    const int* __restrict__ Xtok, const int* __restrict__ Ytok,
    const float* __restrict__ embX, const float* __restrict__ embY,
    const float* __restrict__ WE, const float* __restrict__ WD,
    const float* __restrict__ bE, const float* __restrict__ bD,
    float* __restrict__ xwE, float* __restrict__ xwD)
{
    __shared__ float Al[32][68];
    __shared__ float Bl[32][68];
    __shared__ float Cl[64][68];
    const int tid = threadIdx.x;
    const int phase = blockIdx.z;
    const int* tokens = phase ? Ytok : Xtok;
    const float* emb  = phase ? embY : embX;
    const float* W    = phase ? WD : WE;
    const float* bv   = phase ? bD : bE;
    float* outp       = phase ? xwD : xwE;

    const int m0 = blockIdx.x * 64;
    const int n0 = blockIdx.y * 64;
    const int tm = tid & 15;
    const int tn = tid >> 4;

    float acc[4][4] = {};

    for (int kc = 0; kc < EMBD; kc += 32) {
#pragma unroll
        for (int r = 0; r < 2; ++r) {
            int i = tid + r * 256;
            int am = i >> 3;
            int kq = i & 7;
            int m = m0 + am;
            int t = m >> 5, b = m & 31;
            int tok;
            if (phase) { int tt = (t == 0) ? 0 : (t - 1); tok = tokens[b * LSEQ + tt]; }
            else       { tok = tokens[b * LSEQ + t]; }
            float4 av = *(const float4*)&emb[(size_t)tok * EMBD + kc + kq * 4];
            Al[kq * 4 + 0][am] = av.x; Al[kq * 4 + 1][am] = av.y;
            Al[kq * 4 + 2][am] = av.z; Al[kq * 4 + 3][am] = av.w;
            float4 wv = *(const float4*)&W[(size_t)(n0 + am) * EMBD + kc + kq * 4];
            Bl[kq * 4 + 0][am] = wv.x; Bl[kq * 4 + 1][am] = wv.y;
            Bl[kq * 4 + 2][am] = wv.z; Bl[kq * 4 + 3][am] = wv.w;
        }
        __syncthreads();
#pragma unroll
        for (int k = 0; k < 32; ++k) {
            float4 a  = *(const float4*)&Al[k][tm * 4];
            float4 b4 = *(const float4*)&Bl[k][tn * 4];
            acc[0][0] += a.x * b4.x; acc[0][1] += a.x * b4.y; acc[0][2] += a.x * b4.z; acc[0][3] += a.x * b4.w;
            acc[1][0] += a.y * b4.x; acc[1][1] += a.y * b4.y; acc[1][2] += a.y * b4.z; acc[1][3] += a.y * b4.w;
            acc[2][0] += a.z * b4.x; acc[2][1] += a.z * b4.y; acc[2][2] += a.z * b4.z; acc[2][3] += a.z * b4.w;
            acc[3][0] += a.w * b4.x; acc[3][1] += a.w * b4.y; acc[3][2] += a.w * b4.z; acc[3][3] += a.w * b4.w;
        }
        __syncthreads();
    }

    float4 bb = *(const float4*)&bv[n0 + tn * 4];
#pragma unroll
    for (int r = 0; r < 4; ++r) {
        Cl[tn * 4 + 0][tm * 4 + r] = acc[r][0] + bb.x;
        Cl[tn * 4 + 1][tm * 4 + r] = acc[r][1] + bb.y;
        Cl[tn * 4 + 2][tm * 4 + r] = acc[r][2] + bb.z;
        Cl[tn * 4 + 3][tm * 4 + r] = acc[r][3] + bb.w;
    }
    __syncthreads();

    const int t0 = m0 >> 5;
#pragma unroll
    for (int r = 0; r < 4; ++r) {
        int f = tid + r * 256;
        int nl = f >> 4;
        int rem = f & 15;
        int tp = rem >> 3;
        int bq = rem & 7;
        float4 v = *(const float4*)&Cl[nl][tp * 32 + bq * 4];
        *(float4*)&outp[((size_t)(t0 + tp) * G4 + n0 + nl) * 32 + bq * 4] = v;
    }
}

// ---------------------------------------------------------------------------
// Kernel 1b: WhhE/WhhD (f32 [2048][512]) -> bf16 hi/lo planes (for MFMA A).
// ---------------------------------------------------------------------------
__global__ __launch_bounds__(256) void convWhh_kernel(
    const float* __restrict__ WE, const float* __restrict__ WD,
    short* __restrict__ HiE, short* __restrict__ LoE,
    short* __restrict__ HiD, short* __restrict__ LoD)
{
    int idx = blockIdx.x * 256 + threadIdx.x;     // 2 mats x 131072 chunks
    int m = idx >> 17;
    int e = idx & 131071;
    const float* W = m ? WD : WE;
    short* Hi = m ? HiD : HiE;
    short* Lo = m ? LoD : LoE;
    size_t e0 = (size_t)e * 8;
    float4 v0 = *(const float4*)&W[e0];
    float4 v1 = *(const float4*)&W[e0 + 4];
    float xs[8] = {v0.x, v0.y, v0.z, v0.w, v1.x, v1.y, v1.z, v1.w};
    s16x8 h8, l8;
#pragma unroll
    for (int j = 0; j < 8; ++j) {
        unsigned short hi = f2bf_rn(xs[j]);
        h8[j] = (short)hi;
        l8[j] = (short)f2bf_rn(xs[j] - bf2f(hi));
    }
    *(s16x8*)&Hi[e0] = h8;
    *(s16x8*)&Lo[e0] = l8;
}

// ---------------------------------------------------------------------------
// Kernel 2: LSTM recurrence on MATRIX CORES. 32 blocks x 512 threads.
// Block owns 16 h-cols (64 gate rows: lr = g*16+j, global row g*512+bid*16+j).
// Exchange: per-step buffers of {u32 = bf16hi | bf16lo<<16, u32 tag} pairs,
// layout [col][b]; poll/retry identical to R7 (16 x 16B sc1 loads per thread).
// Waves stage their 64-col window into padded LDS planes hb_hi/lo[32][520],
// barrier B1, then wave (rt,bt) computes its 16x16 gate tile over full K=512
// via 48 mfma_f32_16x16x32_bf16 (3-segment split-bf16; Whh hi/lo frags held
// in 128 VGPRs, loaded once per phase). gbuf parity buffer + B2, then each
// thread does gates for one (col j, b), updates c in-register, publishes one
// 8B {hilo, tag} pair. Two raw barriers per step, no vmcnt drains.
// ---------------------------------------------------------------------------
__global__ __launch_bounds__(512, 2) void lstm_coop_kernel(
    const float* __restrict__ xwE, const float* __restrict__ xwD,
    const short* __restrict__ WhE_hi, const short* __restrict__ WhE_lo,
    const short* __restrict__ WhD_hi, const short* __restrict__ WhD_lo,
    float* __restrict__ H)
{
    __shared__ unsigned short hb_hi[32][520];   // 33.3 KB, [b][k], +8 pad
    __shared__ unsigned short hb_lo[32][520];   // 33.3 KB
    __shared__ float gbuf[2][64][32];           // 16 KB, parity ping-pong

    const int tid = threadIdx.x;
    const int bid = blockIdx.x;
    const int lane = tid & 63;
    const int w = tid >> 6;              // 8 waves
    const int rt = w >> 1;               // row-tile 0..3 (= gate)
    const int bt = w & 1;                // batch-tile 0..1
    const int arow = lane & 15;          // A-frag row-in-tile
    const int koff = (lane >> 4) * 8;    // frag k offset
    const int bb = bt * 16 + (lane & 15);// B-frag batch col
    const int grow0 = rt * 16 + (lane >> 4) * 4;  // C row base in gbuf
    const int gcol = bt * 16 + (lane & 15);       // C col (batch)
    const int j = tid >> 5;              // gate-thread col 0..15
    const int b = tid & 31;              // gate-thread batch
    const int base = w << 4;             // poll slice base (4-col slices)
    float creg = 0.f;

    s16x8 AH[16], AL[16];                // Whh hi/lo frags, resident in VGPRs

    for (int s = 0; s < 2 * LSEQ; ++s) {
        const int phase = s >> 6;
        const int t = s & 63;
        if (t == 0) {                    // (re)load A frags for this phase
            const short* WH = phase ? WhD_hi : WhE_hi;
            const short* WL = phase ? WhD_lo : WhE_lo;
            size_t abase = ((size_t)(rt * 512 + bid * 16 + arow)) * 512 + koff;
#pragma unroll
            for (int kt = 0; kt < 16; ++kt) {
                AH[kt] = *(const s16x8*)&WH[abase + kt * 32];
                AL[kt] = *(const s16x8*)&WL[abase + kt * 32];
            }
        }

        // xw prefetch (h-independent, overlaps the poll)
        const float* xw = phase ? xwD : xwE;
        size_t xb = ((size_t)t * G4 + bid * 16 + j) * 32 + b;
        float xg0 = xw[xb];
        float xg1 = xw[xb + 1 * 512 * 32];
        float xg2 = xw[xb + 2 * 512 * 32];
        float xg3 = xw[xb + 3 * 512 * 32];

        // poll: 16B sc1 loads, selective reload of stale slices (R7-proven)
        const float* sp0 = H + (size_t)s * HSZ2 + (size_t)base * 256 + (size_t)lane * 4;
        uintx4 v[16];
        unsigned pend = 0xffffu;
        do {
#pragma unroll
            for (int ii = 0; ii < 16; ++ii) {
                if (pend & (1u << ii)) {
                    asm volatile("global_load_dwordx4 %0, %1, off offset:%c2 sc1"
                                 : "=v"(v[ii])
                                 : "v"(sp0 + (ii & ~3) * 256), "i"((ii & 3) * 1024));
                }
            }
            asm volatile("s_waitcnt vmcnt(0)" ::: "memory");
            __builtin_amdgcn_sched_barrier(0);
            int ok[16];
            int okall = 1;
#pragma unroll
            for (int ii = 0; ii < 16; ++ii) {
                ok[ii] = 1;
                if (pend & (1u << ii)) {
                    ok[ii] = (v[ii].y == (unsigned)s) & (v[ii].w == (unsigned)s);
                    okall &= ok[ii];
                }
            }
            if (__all(okall)) break;
            unsigned still = 0u;
#pragma unroll
            for (int ii = 0; ii < 16; ++ii)
                if ((pend & (1u << ii)) && !__all(ok[ii])) still |= (1u << ii);
            pend = still;
            if (pend) __builtin_amdgcn_s_sleep(1);
        } while (pend);

        // stage this wave's 64 cols into hb planes ([b][k], 2B scattered)
        {
            const int b0 = 2 * (lane & 15);
            const int cl = lane >> 4;
#pragma unroll
            for (int ii = 0; ii < 16; ++ii) {
                int c = 4 * (base + ii) + cl;
                hb_hi[b0][c]     = (unsigned short)(v[ii].x);
                hb_lo[b0][c]     = (unsigned short)(v[ii].x >> 16);
                hb_hi[b0 + 1][c] = (unsigned short)(v[ii].z);
                hb_lo[b0 + 1][c] = (unsigned short)(v[ii].z >> 16);
            }
        }
        asm volatile("s_waitcnt lgkmcnt(0)\ns_barrier" ::: "memory");  // B1

        // 48 MFMA: gates tile = (Ahi+Alo)@(Bhi+Blo) - Alo@Blo (dropped)
        f32x4 a0 = {}, a1 = {}, a2 = {};
#pragma unroll
        for (int kt = 0; kt < 16; ++kt) {
            s16x8 bhv = *(const s16x8*)&hb_hi[bb][kt * 32 + koff];
            s16x8 blv = *(const s16x8*)&hb_lo[bb][kt * 32 + koff];
            a0 = __builtin_amdgcn_mfma_f32_16x16x32_bf16(AH[kt], bhv, a0, 0, 0, 0);
            a1 = __builtin_amdgcn_mfma_f32_16x16x32_bf16(AL[kt], bhv, a1, 0, 0, 0);
            a2 = __builtin_amdgcn_mfma_f32_16x16x32_bf16(AH[kt], blv, a2, 0, 0, 0);
        }
        const int p = s & 1;
#pragma unroll
        for (int r = 0; r < 4; ++r)
            gbuf[p][grow0 + r][gcol] = a0[r] + a1[r] + a2[r];
        asm volatile("s_waitcnt lgkmcnt(0)\ns_barrier" ::: "memory");  // B2

        // gates + state update + publish (all 512 threads: one (j,b) each)
        {
            float gi = xg0 + gbuf[p][j][b];
            float gf = xg1 + gbuf[p][16 + j][b];
            float gg = xg2 + gbuf[p][32 + j][b];
            float go = xg3 + gbuf[p][48 + j][b];
            float si = 1.f / (1.f + __expf(-gi));
            float sf = 1.f / (1.f + __expf(-gf));
            float so = 1.f / (1.f + __expf(-go));
            float tg = tanhf(gg);
            float c = sf * creg + si * tg;
            creg = c;
            float h = so * tanhf(c);
            unsigned hi = f2bf_rn(h);
            unsigned lo = f2bf_rn(h - bf2f((unsigned short)hi));
            unsigned long long pv =
                ((unsigned long long)(unsigned)(s + 1) << 32) | (hi | (lo << 16));
            __hip_atomic_store(
                (unsigned long long*)H + (size_t)(s + 1) * (HSZ2 / 2)
                    + (size_t)(bid * 16 + j) * 32 + b,
                pv, __ATOMIC_RELAXED, __HIP_MEMORY_SCOPE_AGENT);
        }
        // no end-of-step barrier: gbuf parity + program order protect WAR
    }
}

// ---------------------------------------------------------------------------
// Kernel 4a: fcW (f32) -> Bhi/Blo (bf16). Runs after lstm.
// ---------------------------------------------------------------------------
__global__ __launch_bounds__(256) void convW_kernel(
    const float* __restrict__ W, short* __restrict__ Bhi, short* __restrict__ Blo)
{
    size_t idx = (size_t)blockIdx.x * 256 + threadIdx.x;
    size_t e0 = idx * 8;
    float4 v0 = *(const float4*)&W[e0];
    float4 v1 = *(const float4*)&W[e0 + 4];
    float xs[8] = {v0.x, v0.y, v0.z, v0.w, v1.x, v1.y, v1.z, v1.w};
    s16x8 h8, l8;
#pragma unroll
    for (int j = 0; j < 8; ++j) {
        unsigned short hi = f2bf_rn(xs[j]);
        h8[j] = (short)hi;
        l8[j] = (short)f2bf_rn(xs[j] - bf2f(hi));
    }
    *(s16x8*)&Bhi[e0] = h8;
    *(s16x8*)&Blo[e0] = l8;
}

// ---------------------------------------------------------------------------
// Kernel 4b: decoder H ({hilo,tag} pairs) -> Ahi/Alo bf16 [2048][512].
// hi/lo are consumed directly (they ARE the recurrence's h representation).
// ---------------------------------------------------------------------------
__global__ __launch_bounds__(256) void convA_kernel(
    const float* __restrict__ H65, short* __restrict__ Ahi, short* __restrict__ Alo)
{
    int idx = blockIdx.x * 256 + threadIdx.x;   // 131072 = 2048 m x 64 k8
    int m = idx & 2047;
    int k8 = idx >> 11;
    int t = m >> 5, b = m & 31;
    const unsigned* Hs = (const unsigned*)(H65 + (size_t)t * HSZ2);
    s16x8 h8, l8;
#pragma unroll
    for (int j = 0; j < 8; ++j) {
        int k = k8 * 8 + j;
        unsigned u = Hs[(size_t)(k * 32 + b) * 2];
        h8[j] = (short)(u & 0xffffu);
        l8[j] = (short)(u >> 16);
    }
    *(s16x8*)&Ahi[(size_t)m * 512 + k8 * 8] = h8;
    *(s16x8*)&Alo[(size_t)m * 512 + k8 * 8] = l8;
}

// ---------------------------------------------------------------------------
// Kernel 5: FC via split-bf16 MFMA. C = Ahi*Bhi + Alo*Bhi + Ahi*Blo (+bias).
// 128x128 tile, 4 waves, K-step 64, global_load_lds(16), 16x16x32 bf16 MFMA.
// ---------------------------------------------------------------------------
__global__ __launch_bounds__(256) void fc_mfma_kernel(
    const short* __restrict__ Ahi, const short* __restrict__ Alo,
    const short* __restrict__ Bhi, const short* __restrict__ Blo,
    const float* __restrict__ bias, float* __restrict__ out)
{
    __shared__ short As[128 * 64];
    __shared__ short Bs[128 * 64];

    const int bi = blockIdx.x;
    const int wg = (bi & 7) * 500 + (bi >> 3);    // XCD-contiguous remap
    const int mt = wg & 15, nt = wg >> 4;
    const int m0 = mt * 128, n0 = nt * 128;
    const int tid = threadIdx.x;
    const int w = tid >> 6, lane = tid & 63;
    const int wm = w >> 1, wn = w & 1;
    const int srow = (lane >> 3);
    const int scol = (lane & 7) * 8;

    f32x4 acc[4][4] = {};

    for (int ks = 0; ks < 24; ++ks) {
        const int seg = ks >> 3;                  // 0: hi*hi 1: lo*hi 2: hi*lo
        const int kco = (ks & 7) * 64;
        const short* Asrc = (seg == 1) ? Alo : Ahi;
        const short* Bsrc = (seg == 2) ? Blo : Bhi;
#pragma unroll
        for (int i = 0; i < 4; ++i) {
            int row = w * 32 + i * 8 + srow;
            gload_lds16(&Asrc[(size_t)(m0 + row) * 512 + kco + scol],
                        (void*)&As[w * 2048 + i * 512]);
            gload_lds16(&Bsrc[(size_t)(n0 + row) * 512 + kco + scol],
                        (void*)&Bs[w * 2048 + i * 512]);
        }
        __syncthreads();

#pragma unroll
        for (int kk = 0; kk < 2; ++kk) {
            s16x8 af[4], bf[4];
#pragma unroll
            for (int f = 0; f < 4; ++f) {
                af[f] = *(const s16x8*)&As[(wm * 64 + f * 16 + (lane & 15)) * 64 + kk * 32 + (lane >> 4) * 8];
                bf[f] = *(const s16x8*)&Bs[(wn * 64 + f * 16 + (lane & 15)) * 64 + kk * 32 + (lane >> 4) * 8];
            }
#pragma unroll
            for (int fm = 0; fm < 4; ++fm)
#pragma unroll
                for (int fn = 0; fn < 4; ++fn)
                    acc[fm][fn] = __builtin_amdgcn_mfma_f32_16x16x32_bf16(
                        af[fm], bf[fn], acc[fm][fn], 0, 0, 0);
        }
        __syncthreads();
    }

    float bb[4];
#pragma unroll
    for (int fn = 0; fn < 4; ++fn)
        bb[fn] = bias[n0 + wn * 64 + fn * 16 + (lane & 15)];

#pragma unroll
    for (int fm = 0; fm < 4; ++fm) {
        int mbase = m0 + wm * 64 + fm * 16 + (lane >> 4) * 4;
#pragma unroll
        for (int r = 0; r < 4; ++r) {
            int m = mbase + r;
            int t = m >> 5, b = m & 31;
            float* orow = out + (size_t)(b * LSEQ + t) * VOC;
#pragma unroll
            for (int fn = 0; fn < 4; ++fn)
                orow[n0 + wn * 64 + fn * 16 + (lane & 15)] = acc[fm][fn][r] + bb[fn];
        }
    }
}

// ---------------------------------------------------------------------------
extern "C" void kernel_launch(void* const* d_in, const int* in_sizes, int n_in,
                              void* d_out, int out_size, void* d_ws, size_t ws_size,
                              hipStream_t stream)
{
    const int*   X    = (const int*)d_in[0];
    const int*   y    = (const int*)d_in[1];
    // d_in[2] = teacher_forcing (always 1, unused)
    const float* embX = (const float*)d_in[3];
    const float* WihE = (const float*)d_in[4];
    const float* WhhE = (const float*)d_in[5];
    const float* bE   = (const float*)d_in[6];
    const float* embY = (const float*)d_in[7];
    const float* WihD = (const float*)d_in[8];
    const float* WhhD = (const float*)d_in[9];
    const float* bD   = (const float*)d_in[10];
    const float* fcW  = (const float*)d_in[11];
    const float* fcB  = (const float*)d_in[12];
    float* out = (float*)d_out;

    char* ws = (char*)d_ws;
    const size_t XW_BYTES = (size_t)2048 * 2048 * 4;          // 16 MB each
    const size_t H_BYTES  = (size_t)129 * HSZ2 * 4;           // 16.9 MB
    const size_t A_BYTES  = (size_t)2048 * HID * 2;           // 2 MB each
    const size_t WP_BYTES = (size_t)G4 * HID * 2;             // 2 MB per plane

    float* xwE = (float*)(ws);
    float* xwD = (float*)(ws + XW_BYTES);
    float* H   = (float*)(ws + 2 * XW_BYTES);
    short* Ahi = (short*)(ws + 2 * XW_BYTES + H_BYTES);
    short* Alo = (short*)(ws + 2 * XW_BYTES + H_BYTES + A_BYTES);
    short* Bhi = (short*)(ws);                                 // aliases xw (dead post-lstm)
    short* Blo = (short*)(ws + 2 * XW_BYTES + H_BYTES + 2 * A_BYTES);
    // Whh planes park inside the Blo region: live [convWhh .. end of lstm],
    // Blo is written only after lstm (by convW) -> no temporal overlap.
    short* WhE_hi = Blo;
    short* WhE_lo = (short*)((char*)Blo + WP_BYTES);
    short* WhD_hi = (short*)((char*)Blo + 2 * WP_BYTES);
    short* WhD_lo = (short*)((char*)Blo + 3 * WP_BYTES);

    // reset all H tags every launch (honest sync across graph replays);
    // H[0] = {hilo=0, tag=0} is the step-0 input (h=0).
    hipMemsetAsync((void*)H, 0, H_BYTES, stream);

    convWhh_kernel<<<1024, 256, 0, stream>>>(WhhE, WhhD, WhE_hi, WhE_lo, WhD_hi, WhD_lo);

    input_proj_kernel<<<dim3(32, 32, 2), 256, 0, stream>>>(
        X, y, embX, embY, WihE, WihD, bE, bD, xwE, xwD);

    {
        const float* a0 = xwE; const float* a1 = xwD;
        const short* a2 = WhE_hi; const short* a3 = WhE_lo;
        const short* a4 = WhD_hi; const short* a5 = WhD_lo;
        float* a6 = H;
        void* args[] = {&a0, &a1, &a2, &a3, &a4, &a5, &a6};
        hipLaunchCooperativeKernel((const void*)lstm_coop_kernel, dim3(NBLK), dim3(NTHR),
                                   args, 0, stream);
    }

    convW_kernel<<<8000, 256, 0, stream>>>(fcW, Bhi, Blo);   // overwrites Whh planes (dead)
    convA_kernel<<<512, 256, 0, stream>>>(H + (size_t)65 * HSZ2, Ahi, Alo);

    fc_mfma_kernel<<<4000, 256, 0, stream>>>(Ahi, Alo, Bhi, Blo, fcB, out);
}

// Round 10
// 1044.788 us; speedup vs baseline: 1.3796x; 1.0330x over previous
//
#include <hip/hip_runtime.h>

#define HID 512
#define G4 2048      // 4*HID
#define LSEQ 64
#define VOC 32000
#define EMBD 256
#define NBLK 32      // lstm blocks (one per 16 h-columns, 64 gate rows)
#define NTHR 512     // 8 waves = 4 row-tiles x 2 batch-tiles
#define HSTEP 16384  // u32 entries per per-step h buffer (64 KB): [col][b]

using s16x8 = __attribute__((ext_vector_type(8))) short;   // 8 bf16 (4 VGPR)
using f32x4 = __attribute__((ext_vector_type(4))) float;   // MFMA acc frag
using uintx4 = __attribute__((ext_vector_type(4))) unsigned; // 16B load payload

__device__ inline unsigned short f2bf_rn(float x) {
    unsigned u = __float_as_uint(x);
    unsigned r = (u + 0x7fffu + ((u >> 16) & 1u)) >> 16;
    return (unsigned short)r;
}
__device__ inline float bf2f(unsigned short h) {
    return __uint_as_float(((unsigned)h) << 16);
}
__device__ inline void gload_lds16(const void* g, void* l) {
    __builtin_amdgcn_global_load_lds(
        (const __attribute__((address_space(1))) void*)g,
        (__attribute__((address_space(3))) void*)l, 16, 0, 0);
}

// ---------------------------------------------------------------------------
// Kernel 1: input projection (encoder & decoder). Produces xwT layout:
// xwT[(t*2048 + g*512 + col)*32 + b]. 64x64 tile GEMM + LDS transpose.
// ---------------------------------------------------------------------------
__global__ __launch_bounds__(256) void input_proj_kernel(
    const int* __restrict__ Xtok, const int* __restrict__ Ytok,
    const float* __restrict__ embX, const float* __restrict__ embY,
    const float* __restrict__ WE, const float* __restrict__ WD,
    const float* __restrict__ bE, const float* __restrict__ bD,
    float* __restrict__ xwE, float* __restrict__ xwD)
{
    __shared__ float Al[32][68];
    __shared__ float Bl[32][68];
    __shared__ float Cl[64][68];
    const int tid = threadIdx.x;
    const int phase = blockIdx.z;
    const int* tokens = phase ? Ytok : Xtok;
    const float* emb  = phase ? embY : embX;
    const float* W    = phase ? WD : WE;
    const float* bv   = phase ? bD : bE;
    float* outp       = phase ? xwD : xwE;

    const int m0 = blockIdx.x * 64;
    const int n0 = blockIdx.y * 64;
    const int tm = tid & 15;
    const int tn = tid >> 4;

    float acc[4][4] = {};

    for (int kc = 0; kc < EMBD; kc += 32) {
#pragma unroll
        for (int r = 0; r < 2; ++r) {
            int i = tid + r * 256;
            int am = i >> 3;
            int kq = i & 7;
            int m = m0 + am;
            int t = m >> 5, b = m & 31;
            int tok;
            if (phase) { int tt = (t == 0) ? 0 : (t - 1); tok = tokens[b * LSEQ + tt]; }
            else       { tok = tokens[b * LSEQ + t]; }
            float4 av = *(const float4*)&emb[(size_t)tok * EMBD + kc + kq * 4];
            Al[kq * 4 + 0][am] = av.x; Al[kq * 4 + 1][am] = av.y;
            Al[kq * 4 + 2][am] = av.z; Al[kq * 4 + 3][am] = av.w;
            float4 wv = *(const float4*)&W[(size_t)(n0 + am) * EMBD + kc + kq * 4];
            Bl[kq * 4 + 0][am] = wv.x; Bl[kq * 4 + 1][am] = wv.y;
            Bl[kq * 4 + 2][am] = wv.z; Bl[kq * 4 + 3][am] = wv.w;
        }
        __syncthreads();
#pragma unroll
        for (int k = 0; k < 32; ++k) {
            float4 a  = *(const float4*)&Al[k][tm * 4];
            float4 b4 = *(const float4*)&Bl[k][tn * 4];
            acc[0][0] += a.x * b4.x; acc[0][1] += a.x * b4.y; acc[0][2] += a.x * b4.z; acc[0][3] += a.x * b4.w;
            acc[1][0] += a.y * b4.x; acc[1][1] += a.y * b4.y; acc[1][2] += a.y * b4.z; acc[1][3] += a.y * b4.w;
            acc[2][0] += a.z * b4.x; acc[2][1] += a.z * b4.y; acc[2][2] += a.z * b4.z; acc[2][3] += a.z * b4.w;
            acc[3][0] += a.w * b4.x; acc[3][1] += a.w * b4.y; acc[3][2] += a.w * b4.z; acc[3][3] += a.w * b4.w;
        }
        __syncthreads();
    }

    float4 bb = *(const float4*)&bv[n0 + tn * 4];
#pragma unroll
    for (int r = 0; r < 4; ++r) {
        Cl[tn * 4 + 0][tm * 4 + r] = acc[r][0] + bb.x;
        Cl[tn * 4 + 1][tm * 4 + r] = acc[r][1] + bb.y;
        Cl[tn * 4 + 2][tm * 4 + r] = acc[r][2] + bb.z;
        Cl[tn * 4 + 3][tm * 4 + r] = acc[r][3] + bb.w;
    }
    __syncthreads();

    const int t0 = m0 >> 5;
#pragma unroll
    for (int r = 0; r < 4; ++r) {
        int f = tid + r * 256;
        int nl = f >> 4;
        int rem = f & 15;
        int tp = rem >> 3;
        int bq = rem & 7;
        float4 v = *(const float4*)&Cl[nl][tp * 32 + bq * 4];
        *(float4*)&outp[((size_t)(t0 + tp) * G4 + n0 + nl) * 32 + bq * 4] = v;
    }
}

// ---------------------------------------------------------------------------
// Kernel 1b: WhhE/WhhD (f32 [2048][512]) -> bf16 hi/lo planes (for MFMA A).
// ---------------------------------------------------------------------------
__global__ __launch_bounds__(256) void convWhh_kernel(
    const float* __restrict__ WE, const float* __restrict__ WD,
    short* __restrict__ HiE, short* __restrict__ LoE,
    short* __restrict__ HiD, short* __restrict__ LoD)
{
    int idx = blockIdx.x * 256 + threadIdx.x;     // 2 mats x 131072 chunks
    int m = idx >> 17;
    int e = idx & 131071;
    const float* W = m ? WD : WE;
    short* Hi = m ? HiD : HiE;
    short* Lo = m ? LoD : LoE;
    size_t e0 = (size_t)e * 8;
    float4 v0 = *(const float4*)&W[e0];
    float4 v1 = *(const float4*)&W[e0 + 4];
    float xs[8] = {v0.x, v0.y, v0.z, v0.w, v1.x, v1.y, v1.z, v1.w};
    s16x8 h8, l8;
#pragma unroll
    for (int j = 0; j < 8; ++j) {
        unsigned short hi = f2bf_rn(xs[j]);
        h8[j] = (short)hi;
        l8[j] = (short)f2bf_rn(xs[j] - bf2f(hi));
    }
    *(s16x8*)&Hi[e0] = h8;
    *(s16x8*)&Lo[e0] = l8;
}

// ---------------------------------------------------------------------------
// Kernel 2: LSTM recurrence on matrix cores — flags + read-once exchange.
// 32 blocks x 512 threads; block owns 16 h-cols (64 gate rows).
// Per-step h buffer: u32 (bf16hi | bf16lo<<16), layout [col][b] (64 KB).
// Producer: publish u32 (coalesced), __syncthreads (vmcnt(0) drain), tid0
// RELEASE-stores flags[bid] = s+1.  Consumer: ONE wave-load polls all 32
// flags (lane i -> flag i); on __all(f>=s), 8 x 16B sc1 loads fetch the
// wave's 64-col window ONCE; stage into XOR-swizzled hb planes.
// SWIZZLE FIX vs R9: row stride is 1024 B (2^10) so row bases have zero
// bits in the XOR field (bits 4-6) => addr = (b<<10 | cb) ^ ((b&7)<<4) is
// BIJECTIVE (R9's 1040-B stride caused cross-row write collisions).
// ---------------------------------------------------------------------------
__global__ __launch_bounds__(512, 2) void lstm_coop_kernel(
    const float* __restrict__ xwE, const float* __restrict__ xwD,
    const short* __restrict__ WhE_hi, const short* __restrict__ WhE_lo,
    const short* __restrict__ WhD_hi, const short* __restrict__ WhD_lo,
    unsigned* __restrict__ H32, int* __restrict__ flags)
{
    __shared__ char hb_hi[32 * 1024];           // 32 KB, [b][c] bf16, swizzled
    __shared__ char hb_lo[32 * 1024];           // 32 KB
    __shared__ float gbuf[2][64][32];           // 16 KB, parity ping-pong

    const int tid = threadIdx.x;
    const int bid = blockIdx.x;
    const int lane = tid & 63;
    const int w = tid >> 6;              // 8 waves
    const int rt = w >> 1;               // row-tile 0..3 (= gate)
    const int bt = w & 1;                // batch-tile 0..1
    const int arow = lane & 15;          // A-frag row-in-tile
    const int koff = (lane >> 4) * 8;    // frag k offset (shorts)
    const int bb = bt * 16 + (lane & 15);// B-frag batch row in hb
    const int grow0 = rt * 16 + (lane >> 4) * 4;  // C row base in gbuf
    const int gcol = bt * 16 + (lane & 15);       // C col (batch)
    const int j = tid >> 5;              // gate-thread col 0..15
    const int b = tid & 31;              // gate-thread batch
    // per-lane offset within the wave's 8KB window: c_local = lane>>3, b0 = 4*(lane&7)
    const int lane_off = ((lane >> 3) << 7) | ((lane & 7) << 4);
    float creg = 0.f;

    s16x8 AH[16], AL[16];                // Whh hi/lo frags, resident in VGPRs

    for (int s = 0; s < 2 * LSEQ; ++s) {
        const int phase = s >> 6;
        const int t = s & 63;
        if (t == 0) {                    // (re)load A frags for this phase
            const short* WH = phase ? WhD_hi : WhE_hi;
            const short* WL = phase ? WhD_lo : WhE_lo;
            size_t abase = ((size_t)(rt * 512 + bid * 16 + arow)) * 512 + koff;
#pragma unroll
            for (int kt = 0; kt < 16; ++kt) {
                AH[kt] = *(const s16x8*)&WH[abase + kt * 32];
                AL[kt] = *(const s16x8*)&WL[abase + kt * 32];
            }
        }

        // xw prefetch (h-independent, overlaps the poll)
        const float* xw = phase ? xwD : xwE;
        size_t xb = ((size_t)t * G4 + bid * 16 + j) * 32 + b;
        float xg0 = xw[xb];
        float xg1 = xw[xb + 1 * 512 * 32];
        float xg2 = xw[xb + 2 * 512 * 32];
        float xg3 = xw[xb + 3 * 512 * 32];

        // poll all 32 producer flags with one wave-load per round
        {
            const int* flagp = flags + (lane & 31) * 32;   // 128B-strided lines
            for (;;) {
                int f = __hip_atomic_load(flagp, __ATOMIC_RELAXED,
                                          __HIP_MEMORY_SCOPE_AGENT);
                if (__all(f >= s)) break;
                __builtin_amdgcn_s_sleep(1);
            }
        }

        // data read ONCE: 8 x 16B sc1 loads cover this wave's 64-col window
        const char* wptr = (const char*)(H32 + (size_t)s * HSTEP)
                           + (w << 13) + lane_off;
        uintx4 v[8];
#pragma unroll
        for (int ii = 0; ii < 8; ++ii) {
            asm volatile("global_load_dwordx4 %0, %1, off offset:%c2 sc1"
                         : "=v"(v[ii])
                         : "v"(wptr + (ii >> 2) * 4096), "i"((ii & 3) * 1024));
        }
        asm volatile("s_waitcnt vmcnt(0)" ::: "memory");
        __builtin_amdgcn_sched_barrier(0);

        // stage into swizzled hb planes: entry (c = 64w+8ii+(lane>>3), b = 4*(lane&7)+q)
        {
            const int c2 = 2 * (64 * w + (lane >> 3));   // byte col offset
            const int bq0 = 4 * (lane & 7);
#pragma unroll
            for (int ii = 0; ii < 8; ++ii) {
#pragma unroll
                for (int q = 0; q < 4; ++q) {
                    int brow = bq0 + q;
                    unsigned u = v[ii][q];
                    int addr = ((brow << 10) + c2 + 16 * ii) ^ ((brow & 7) << 4);
                    *(unsigned short*)(hb_hi + addr) = (unsigned short)u;
                    *(unsigned short*)(hb_lo + addr) = (unsigned short)(u >> 16);
                }
            }
        }
        asm volatile("s_waitcnt lgkmcnt(0)\ns_barrier" ::: "memory");  // B1

        // 48 MFMA: gates tile = (Ahi+Alo)@(Bhi+Blo) - Alo@Blo (dropped)
        f32x4 a0 = {}, a1 = {}, a2 = {};
#pragma unroll
        for (int kt = 0; kt < 16; ++kt) {
            int raddr = ((bb << 10) + 64 * kt + 2 * koff) ^ ((bb & 7) << 4);
            s16x8 bhv = *(const s16x8*)(hb_hi + raddr);
            s16x8 blv = *(const s16x8*)(hb_lo + raddr);
            a0 = __builtin_amdgcn_mfma_f32_16x16x32_bf16(AH[kt], bhv, a0, 0, 0, 0);
            a1 = __builtin_amdgcn_mfma_f32_16x16x32_bf16(AL[kt], bhv, a1, 0, 0, 0);
            a2 = __builtin_amdgcn_mfma_f32_16x16x32_bf16(AH[kt], blv, a2, 0, 0, 0);
        }
        const int p = s & 1;
#pragma unroll
        for (int r = 0; r < 4; ++r)
            gbuf[p][grow0 + r][gcol] = a0[r] + a1[r] + a2[r];
        asm volatile("s_waitcnt lgkmcnt(0)\ns_barrier" ::: "memory");  // B2

        // gates + state update + publish (all 512 threads: one (j,b) each)
        {
            float gi = xg0 + gbuf[p][j][b];
            float gf = xg1 + gbuf[p][16 + j][b];
            float gg = xg2 + gbuf[p][32 + j][b];
            float go = xg3 + gbuf[p][48 + j][b];
            float si = 1.f / (1.f + __expf(-gi));
            float sf = 1.f / (1.f + __expf(-gf));
            float so = 1.f / (1.f + __expf(-go));
            float tg = tanhf(gg);
            float c = sf * creg + si * tg;
            creg = c;
            float h = so * tanhf(c);
            unsigned hi = f2bf_rn(h);
            unsigned lo = f2bf_rn(h - bf2f((unsigned short)hi));
            __hip_atomic_store(
                H32 + (size_t)(s + 1) * HSTEP + (size_t)(bid * 16 + j) * 32 + b,
                hi | (lo << 16), __ATOMIC_RELAXED, __HIP_MEMORY_SCOPE_AGENT);
        }
        __syncthreads();   // compiler emits vmcnt(0) drain + barrier (m97 note)
        if (tid == 0)
            __hip_atomic_store(&flags[bid * 32], s + 1,
                               __ATOMIC_RELEASE, __HIP_MEMORY_SCOPE_AGENT);
    }
}

// ---------------------------------------------------------------------------
// Kernel 4a: fcW (f32) -> Bhi/Blo (bf16). Runs after lstm.
// ---------------------------------------------------------------------------
__global__ __launch_bounds__(256) void convW_kernel(
    const float* __restrict__ W, short* __restrict__ Bhi, short* __restrict__ Blo)
{
    size_t idx = (size_t)blockIdx.x * 256 + threadIdx.x;
    size_t e0 = idx * 8;
    float4 v0 = *(const float4*)&W[e0];
    float4 v1 = *(const float4*)&W[e0 + 4];
    float xs[8] = {v0.x, v0.y, v0.z, v0.w, v1.x, v1.y, v1.z, v1.w};
    s16x8 h8, l8;
#pragma unroll
    for (int j = 0; j < 8; ++j) {
        unsigned short hi = f2bf_rn(xs[j]);
        h8[j] = (short)hi;
        l8[j] = (short)f2bf_rn(xs[j] - bf2f(hi));
    }
    *(s16x8*)&Bhi[e0] = h8;
    *(s16x8*)&Blo[e0] = l8;
}

// ---------------------------------------------------------------------------
// Kernel 4b: decoder H (u32 hilo, [col][b]) -> Ahi/Alo bf16 [2048][512].
// ---------------------------------------------------------------------------
__global__ __launch_bounds__(256) void convA_kernel(
    const unsigned* __restrict__ H65, short* __restrict__ Ahi, short* __restrict__ Alo)
{
    int idx = blockIdx.x * 256 + threadIdx.x;   // 131072 = 2048 m x 64 k8
    int m = idx & 2047;
    int k8 = idx >> 11;
    int t = m >> 5, b = m & 31;
    const unsigned* Hs = H65 + (size_t)t * HSTEP;
    s16x8 h8, l8;
#pragma unroll
    for (int j = 0; j < 8; ++j) {
        int k = k8 * 8 + j;
        unsigned u = Hs[(size_t)k * 32 + b];
        h8[j] = (short)(u & 0xffffu);
        l8[j] = (short)(u >> 16);
    }
    *(s16x8*)&Ahi[(size_t)m * 512 + k8 * 8] = h8;
    *(s16x8*)&Alo[(size_t)m * 512 + k8 * 8] = l8;
}

// ---------------------------------------------------------------------------
// Kernel 5: FC via split-bf16 MFMA. C = Ahi*Bhi + Alo*Bhi + Ahi*Blo (+bias).
// 128x128 tile, 4 waves, K-step 64, global_load_lds(16), 16x16x32 bf16 MFMA.
// ---------------------------------------------------------------------------
__global__ __launch_bounds__(256) void fc_mfma_kernel(
    const short* __restrict__ Ahi, const short* __restrict__ Alo,
    const short* __restrict__ Bhi, const short* __restrict__ Blo,
    const float* __restrict__ bias, float* __restrict__ out)
{
    __shared__ short As[128 * 64];
    __shared__ short Bs[128 * 64];

    const int bi = blockIdx.x;
    const int wg = (bi & 7) * 500 + (bi >> 3);    // XCD-contiguous remap
    const int mt = wg & 15, nt = wg >> 4;
    const int m0 = mt * 128, n0 = nt * 128;
    const int tid = threadIdx.x;
    const int w = tid >> 6, lane = tid & 63;
    const int wm = w >> 1, wn = w & 1;
    const int srow = (lane >> 3);
    const int scol = (lane & 7) * 8;

    f32x4 acc[4][4] = {};

    for (int ks = 0; ks < 24; ++ks) {
        const int seg = ks >> 3;                  // 0: hi*hi 1: lo*hi 2: hi*lo
        const int kco = (ks & 7) * 64;
        const short* Asrc = (seg == 1) ? Alo : Ahi;
        const short* Bsrc = (seg == 2) ? Blo : Bhi;
#pragma unroll
        for (int i = 0; i < 4; ++i) {
            int row = w * 32 + i * 8 + srow;
            gload_lds16(&Asrc[(size_t)(m0 + row) * 512 + kco + scol],
                        (void*)&As[w * 2048 + i * 512]);
            gload_lds16(&Bsrc[(size_t)(n0 + row) * 512 + kco + scol],
                        (void*)&Bs[w * 2048 + i * 512]);
        }
        __syncthreads();

#pragma unroll
        for (int kk = 0; kk < 2; ++kk) {
            s16x8 af[4], bf[4];
#pragma unroll
            for (int f = 0; f < 4; ++f) {
                af[f] = *(const s16x8*)&As[(wm * 64 + f * 16 + (lane & 15)) * 64 + kk * 32 + (lane >> 4) * 8];
                bf[f] = *(const s16x8*)&Bs[(wn * 64 + f * 16 + (lane & 15)) * 64 + kk * 32 + (lane >> 4) * 8];
            }
#pragma unroll
            for (int fm = 0; fm < 4; ++fm)
#pragma unroll
                for (int fn = 0; fn < 4; ++fn)
                    acc[fm][fn] = __builtin_amdgcn_mfma_f32_16x16x32_bf16(
                        af[fm], bf[fn], acc[fm][fn], 0, 0, 0);
        }
        __syncthreads();
    }

    float bb[4];
#pragma unroll
    for (int fn = 0; fn < 4; ++fn)
        bb[fn] = bias[n0 + wn * 64 + fn * 16 + (lane & 15)];

#pragma unroll
    for (int fm = 0; fm < 4; ++fm) {
        int mbase = m0 + wm * 64 + fm * 16 + (lane >> 4) * 4;
#pragma unroll
        for (int r = 0; r < 4; ++r) {
            int m = mbase + r;
            int t = m >> 5, b = m & 31;
            float* orow = out + (size_t)(b * LSEQ + t) * VOC;
#pragma unroll
            for (int fn = 0; fn < 4; ++fn)
                orow[n0 + wn * 64 + fn * 16 + (lane & 15)] = acc[fm][fn][r] + bb[fn];
        }
    }
}

// ---------------------------------------------------------------------------
extern "C" void kernel_launch(void* const* d_in, const int* in_sizes, int n_in,
                              void* d_out, int out_size, void* d_ws, size_t ws_size,
                              hipStream_t stream)
{
    const int*   X    = (const int*)d_in[0];
    const int*   y    = (const int*)d_in[1];
    // d_in[2] = teacher_forcing (always 1, unused)
    const float* embX = (const float*)d_in[3];
    const float* WihE = (const float*)d_in[4];
    const float* WhhE = (const float*)d_in[5];
    const float* bE   = (const float*)d_in[6];
    const float* embY = (const float*)d_in[7];
    const float* WihD = (const float*)d_in[8];
    const float* WhhD = (const float*)d_in[9];
    const float* bD   = (const float*)d_in[10];
    const float* fcW  = (const float*)d_in[11];
    const float* fcB  = (const float*)d_in[12];
    float* out = (float*)d_out;

    char* ws = (char*)d_ws;
    const size_t XW_BYTES = (size_t)2048 * 2048 * 4;          // 16 MB each
    const size_t FL_BYTES = 64 * 1024;                        // flags (4 KB used)
    const size_t H_BYTES  = (size_t)129 * HSTEP * 4;          // 8.45 MB
    const size_t A_BYTES  = (size_t)2048 * HID * 2;           // 2 MB each
    const size_t WP_BYTES = (size_t)G4 * HID * 2;             // 2 MB per plane

    float*    xwE   = (float*)(ws);
    float*    xwD   = (float*)(ws + XW_BYTES);
    int*      flags = (int*)(ws + 2 * XW_BYTES);
    unsigned* H32   = (unsigned*)(ws + 2 * XW_BYTES + FL_BYTES);
    short*    Ahi   = (short*)(ws + 2 * XW_BYTES + FL_BYTES + H_BYTES);
    short*    Alo   = (short*)(ws + 2 * XW_BYTES + FL_BYTES + H_BYTES + A_BYTES);
    short*    Bhi   = (short*)(ws);                           // aliases xw (dead post-lstm)
    short*    Blo   = (short*)(ws + 2 * XW_BYTES + FL_BYTES + H_BYTES + 2 * A_BYTES);
    // Whh planes park inside the Blo region: live [convWhh .. end of lstm];
    // Blo is written only after the lstm (by convW) -> no temporal overlap.
    short* WhE_hi = Blo;
    short* WhE_lo = (short*)((char*)Blo + WP_BYTES);
    short* WhD_hi = (short*)((char*)Blo + 2 * WP_BYTES);
    short* WhD_lo = (short*)((char*)Blo + 3 * WP_BYTES);

    // reset flags + H[0] (= h0 = 0) each launch: 128 KB total
    hipMemsetAsync((void*)flags, 0, FL_BYTES + (size_t)HSTEP * 4, stream);

    convWhh_kernel<<<1024, 256, 0, stream>>>(WhhE, WhhD, WhE_hi, WhE_lo, WhD_hi, WhD_lo);

    input_proj_kernel<<<dim3(32, 32, 2), 256, 0, stream>>>(
        X, y, embX, embY, WihE, WihD, bE, bD, xwE, xwD);

    {
        const float* a0 = xwE; const float* a1 = xwD;
        const short* a2 = WhE_hi; const short* a3 = WhE_lo;
        const short* a4 = WhD_hi; const short* a5 = WhD_lo;
        unsigned* a6 = H32; int* a7 = flags;
        void* args[] = {&a0, &a1, &a2, &a3, &a4, &a5, &a6, &a7};
        hipLaunchCooperativeKernel((const void*)lstm_coop_kernel, dim3(NBLK), dim3(NTHR),
                                   args, 0, stream);
    }

    convW_kernel<<<8000, 256, 0, stream>>>(fcW, Bhi, Blo);   // overwrites Whh planes (dead)
    convA_kernel<<<512, 256, 0, stream>>>(H32 + (size_t)65 * HSTEP, Ahi, Alo);

    fc_mfma_kernel<<<4000, 256, 0, stream>>>(Ahi, Alo, Bhi, Blo, fcB, out);
}